// Round 2
// baseline (196.274 us; speedup 1.0000x reference)
//
#include <hip/hip_runtime.h>

// mp: [1, 21, 16, 256, 256] fp32
#define CC   21
#define DD   16
#define HH   256
#define WW   256
#define HWP  (HH * WW)      // 65536
#define DHW  (DD * HWP)     // 1048576

typedef float f4a __attribute__((ext_vector_type(4), aligned(16)));
__device__ __forceinline__ f4a f4add(f4a a, f4a b) { return a + b; }

// ---------------------------------------------------------------------------
// K1: D-blur (registers) + H-blur (LDS), persistent-block grid-stride version.
// Per-tile code identical to the verified round-1 kernel; only the outer
// loop is new. 1280 blocks = 5 resident/CU (LDS cap) x 256 CUs; each block
// processes ~4.2 tiles, amortizing workgroup launch/ramp 4x.
// ---------------------------------------------------------------------------
#define AROW 36
#define PYN  12
#define A_SZ (DD * PYN * AROW)   // 6912 floats = 27648 B -> 5 blocks/CU

#define NT1  (8 * 32 * CC)       // 5376 tiles (x:8, y:32, ch:21)
#define G1   1280                // 5 blocks/CU x 256 CU

__global__ __launch_bounds__(256, 5) void dh_blur_kernel(const float* __restrict__ mp,
                                                         float* __restrict__ out) {
    __shared__ float A[A_SZ];
    const int tid = threadIdx.x;

    // tile-independent stage-task constants
    const int s   = (tid >= 96) ? 1 : 0;
    const int col = (tid < 192) ? (tid - s * 96) : 0;
    const int py  = col >> 3;              // 0..11
    const int x4  = col & 7;               // quad 0..7

    for (int t = blockIdx.x; t < NT1; t += G1) {
        const int xb = t & 7;
        const int yb = (t >> 3) & 31;
        const int ch = t >> 8;
        const int w0 = xb * 32;
        const int h0 = yb * 8;
        const float* __restrict__ src = mp + (size_t)ch * DHW;

        if (tid < 192) {
            const int h = min(HH - 1, max(0, h0 + py - 2));
            const float* colp = src + (size_t)h * WW + w0 + x4 * 4;

            f4a l[12];
#pragma unroll
            for (int m = 0; m < 12; ++m) {
                const int dz = s * 8 + m;                 // staged plane 0..19
                const int d  = min(DD - 1, max(0, dz - 2)); // replicate clamp in D
                l[m] = *(const f4a*)(colp + (size_t)d * HWP);
            }
            // identical summation order to the verified kernel:
            f4a sum = f4add(f4add(f4add(l[0], l[1]), f4add(l[2], l[3])), l[4]);
#pragma unroll
            for (int i = 0; i < 8; ++i) {
                *(f4a*)(&A[((s * 8 + i) * PYN + py) * AROW + x4 * 4]) = sum;
                if (i < 7) sum = sum - l[i] + l[i + 5];
            }
        }
        __syncthreads();

        // H pass: tt = dout*64 + y*8 + x4
#pragma unroll
        for (int it = 0; it < 4; ++it) {
            const int tt   = tid + it * 256;
            const int xx4  = tt & 7;
            const int y    = (tt >> 3) & 7;
            const int dout = tt >> 6;

            const float* b = &A[(dout * PYN + y) * AROW + xx4 * 4];
            f4a a = *(const f4a*)b;
#pragma unroll
            for (int k = 1; k < 5; ++k) a = f4add(a, *(const f4a*)(b + k * AROW));

            *(f4a*)(out + (size_t)ch * DHW + (size_t)dout * HWP
                    + (h0 + y) * WW + w0 + xx4 * 4) = a;
        }
        __syncthreads();   // A reused by next tile
    }
}

// ---------------------------------------------------------------------------
// K2: W-blur + weighted-median, persistent-block grid-stride version.
// Per-row code identical to the verified round-1 kernel. 1792 blocks =
// 7 resident/CU (LDS cap) x 256 CUs; each block ~2.3 rows.
// ---------------------------------------------------------------------------
#define ROWP 264   // 2 pad + 2 lo-edge + 256 data + 2 hi-edge + 2 pad

#define NT2  (HH * DD)    // 4096 (d,h) rows
#define G2   1792         // 7 blocks/CU x 256 CU

__global__ __launch_bounds__(256, 7) void wmedian_kernel(float* __restrict__ y4) {
    __shared__ float R[CC * ROWP];
    const int tid = threadIdx.x;

    for (int t = blockIdx.x; t < NT2; t += G2) {
        const int h = t & 255;
        const int d = t >> 8;
        float* __restrict__ base = y4 + (size_t)d * HWP + (size_t)h * WW;

        // stage: 21 rows x 64 aligned float4
        for (int idx = tid; idx < CC * 64; idx += 256) {
            const int c  = idx >> 6;
            const int w4 = idx & 63;
            *(f4a*)(&R[c * ROWP + 4 + w4 * 4]) =
                *(const f4a*)(base + (size_t)c * DHW + w4 * 4);
        }
        // replicate edges
        if (tid < CC) {
            const float v0 = base[(size_t)tid * DHW];
            const float vL = base[(size_t)tid * DHW + (WW - 1)];
            R[tid * ROWP + 2]   = v0;
            R[tid * ROWP + 3]   = v0;
            R[tid * ROWP + 260] = vL;
            R[tid * ROWP + 261] = vL;
        }
        __syncthreads();

        const int w = tid;   // 0..255
        float v[CC];
        float tot = 0.f;
#pragma unroll
        for (int c = 0; c < CC; ++c) {
            const float* r = &R[c * ROWP + 2 + w];           // r[0] = value at w-2
            v[c] = ((((r[0] + r[1]) + r[2]) + r[3]) + r[4]); // same W order as before
            tot += v[c];
        }
        const float inv = 1.0f / tot;

        float ss = 0.f, sv0 = 0.f, sv1 = 0.f;
        int m0 = 0, m1 = 0;
#pragma unroll
        for (int c = 0; c < CC; ++c) {
            const float yn = v[c] * inv;
            const float sn = ss + yn;
            if (c == 0) { sv0 = yn; sv1 = yn; }                           // defaults
            if (v[c] > 0.f && sn < 0.5f) { m0 = c; sv0 = yn; }            // last qualifying
            if (m1 == 0 && c > 0 && sn > 0.5f) { m1 = c; sv1 = yn; }      // first qualifying
            ss = sn;
        }

#pragma unroll
        for (int c = 0; c < CC; ++c) {
            base[(size_t)c * DHW + w] = (c == m0) ? sv0 : ((c == m1) ? sv1 : 0.f);
        }
        __syncthreads();   // R reused by next row
    }
}

extern "C" void kernel_launch(void* const* d_in, const int* in_sizes, int n_in,
                              void* d_out, int out_size, void* d_ws, size_t ws_size,
                              hipStream_t stream) {
    const float* mp = (const float*)d_in[0];
    float* out = (float*)d_out;

    dh_blur_kernel<<<G1, 256, 0, stream>>>(mp, out);    // 1280 persistent blocks
    wmedian_kernel<<<G2, 256, 0, stream>>>(out);        // 1792 persistent blocks
}